// Round 2
// baseline (1010.774 us; speedup 1.0000x reference)
//
#include <hip/hip_runtime.h>

#define B 16384
#define ENC_LEN 48
#define ENC_HID 128
#define T_DEC 12

__device__ __forceinline__ float fast_rcp(float x) { return __builtin_amdgcn_rcpf(x); }
__device__ __forceinline__ float fast_exp(float x) { return __expf(x); }
__device__ __forceinline__ float sigmoidf_(float x) { return fast_rcp(1.f + fast_exp(-x)); }
__device__ __forceinline__ float tanhf_(float x) {
    // 1 - 2/(e^{2x}+1); correct saturation for |x| large (exp->inf => rcp->0 => 1)
    return 1.f - 2.f * fast_rcp(1.f + fast_exp(2.f * x));
}
__device__ __forceinline__ float nan_to_num_(float v) { return (v != v) ? 0.f : v; }

// P[e*B + b] = float4( enc_row(e,b) . comb_W[i, 0:128] ), i = 0..3
// 8 lanes per row; lane l loads float4 at element (k*32 + l*4), k=0..3:
// per load instruction the 8 lanes of a row cover 128 contiguous bytes,
// the wave covers 8 rows -> 1 KB, perfectly coalesced.
__global__ __launch_bounds__(256) void precompute_P_kernel(
    const float* __restrict__ enc,    // (48, B, 128) f32
    const float* __restrict__ cW,     // (4, 132) f32
    float4* __restrict__ P)
{
    const int l = threadIdx.x & 7;          // lane within row group
    const int rowLocal = threadIdx.x >> 3;  // 0..31

    // per-lane weights: w[i][k][j] = cW[i*132 + k*32 + l*4 + j]
    float w[4][4][4];
    #pragma unroll
    for (int i = 0; i < 4; ++i)
        #pragma unroll
        for (int k = 0; k < 4; ++k) {
            float4 t = *(const float4*)(cW + i * 132 + k * 32 + l * 4);
            w[i][k][0] = t.x; w[i][k][1] = t.y; w[i][k][2] = t.z; w[i][k][3] = t.w;
        }

    const int totalRows = ENC_LEN * B;          // 786432
    const int stride = gridDim.x * 32;
    for (int row = blockIdx.x * 32 + rowLocal; row < totalRows; row += stride) {
        const float* r = enc + (size_t)row * ENC_HID;
        float4 e[4];
        #pragma unroll
        for (int k = 0; k < 4; ++k)
            e[k] = *(const float4*)(r + k * 32 + l * 4);

        float a[4];
        #pragma unroll
        for (int i = 0; i < 4; ++i) {
            float s0 = e[0].x * w[i][0][0] + e[0].y * w[i][0][1] + e[0].z * w[i][0][2] + e[0].w * w[i][0][3];
            float s1 = e[1].x * w[i][1][0] + e[1].y * w[i][1][1] + e[1].z * w[i][1][2] + e[1].w * w[i][1][3];
            float s2 = e[2].x * w[i][2][0] + e[2].y * w[i][2][1] + e[2].z * w[i][2][2] + e[2].w * w[i][2][3];
            float s3 = e[3].x * w[i][3][0] + e[3].y * w[i][3][1] + e[3].z * w[i][3][2] + e[3].w * w[i][3][3];
            a[i] = (s0 + s1) + (s2 + s3);
        }
        #pragma unroll
        for (int m = 1; m < 8; m <<= 1) {
            #pragma unroll
            for (int i = 0; i < 4; ++i)
                a[i] += __shfl_xor(a[i], m, 8);
        }
        if (l == 0) P[row] = make_float4(a[0], a[1], a[2], a[3]);
    }
}

// One thread per batch element; 12 sequential steps entirely in registers.
// USE_P=false fallback recomputes the enc projection inline (only if ws too small).
template <bool USE_P>
__global__ __launch_bounds__(256) void decode_kernel(
    const float* __restrict__ y,        // (B,13,4)
    const float* __restrict__ hidden,   // (B,32)
    const float4* __restrict__ P,       // (48,B) f32x4
    const float* __restrict__ enc,      // (48,B,128) (fallback only)
    const float* __restrict__ aW,       // (48,36)
    const float* __restrict__ ab,       // (48)
    const float* __restrict__ cW,       // (4,132)
    const float* __restrict__ cb,       // (4)
    const float* __restrict__ wih,      // (96,4)
    const float* __restrict__ whh,      // (96,32)
    const float* __restrict__ bih,      // (96)
    const float* __restrict__ bhh,      // (96)
    const float* __restrict__ fW,       // (32)
    const float* __restrict__ fb,       // (1)
    float* __restrict__ out)            // (12,B)
{
    const int b = blockIdx.x * blockDim.x + threadIdx.x;   // < B

    float h[32];
    {
        const float4* hp = (const float4*)(hidden + (size_t)b * 32);  // 128 B, aligned
        #pragma unroll
        for (int q = 0; q < 8; ++q) {
            float4 v = hp[q];
            h[q * 4 + 0] = v.x; h[q * 4 + 1] = v.y; h[q * 4 + 2] = v.z; h[q * 4 + 3] = v.w;
        }
    }
    float x[4];
    #pragma unroll
    for (int k = 0; k < 4; ++k)
        x[k] = nan_to_num_(y[(size_t)b * 52 + k]);

    for (int t = 0; t < T_DEC; ++t) {
        // ---- attention: logits + softmax-weighted P, accumulated online ----
        float S = 0.f;
        float cc0 = 0.f, cc1 = 0.f, cc2 = 0.f, cc3 = 0.f;
        for (int ec = 0; ec < 6; ++ec) {               // 6 chunks of 8 enc positions
            float4 pb[8];
            if (USE_P) {
                #pragma unroll
                for (int i = 0; i < 8; ++i)            // issue loads first (L2/L3 latency hide)
                    pb[i] = P[(size_t)(ec * 8 + i) * B + b];
            } else {
                #pragma unroll
                for (int i = 0; i < 8; ++i) {
                    const float* er = enc + ((size_t)(ec * 8 + i) * B + b) * ENC_HID;
                    float p0 = 0.f, p1 = 0.f, p2 = 0.f, p3 = 0.f;
                    for (int d = 0; d < ENC_HID; ++d) {
                        float ev = er[d];
                        p0 += ev * cW[0 * 132 + d];
                        p1 += ev * cW[1 * 132 + d];
                        p2 += ev * cW[2 * 132 + d];
                        p3 += ev * cW[3 * 132 + d];
                    }
                    pb[i] = make_float4(p0, p1, p2, p3);
                }
            }
            #pragma unroll
            for (int i = 0; i < 8; ++i) {
                const int e = ec * 8 + i;
                const float* wr = aW + e * 36;
                float s = ab[e] + wr[0] * x[0] + wr[1] * x[1] + wr[2] * x[2] + wr[3] * x[3];
                #pragma unroll
                for (int j = 0; j < 32; ++j) s += wr[4 + j] * h[j];
                float wgt = fast_exp(s);
                S   += wgt;
                cc0 += wgt * pb[i].x;
                cc1 += wgt * pb[i].y;
                cc2 += wgt * pb[i].z;
                cc3 += wgt * pb[i].w;
            }
        }
        const float rs = fast_rcp(S);
        float x2[4];
        {
            float num[4] = {cc0, cc1, cc2, cc3};
            #pragma unroll
            for (int i = 0; i < 4; ++i) {
                const float* cr = cW + i * 132 + 128;
                x2[i] = num[i] * rs + cr[0] * x[0] + cr[1] * x[1] + cr[2] * x[2] + cr[3] * x[3] + cb[i];
            }
        }
        // ---- GRU cell ----
        float hn[32];
        #pragma unroll
        for (int g = 0; g < 32; ++g) {
            float ir = bih[g], iz = bih[g + 32], inn = bih[g + 64];
            #pragma unroll
            for (int k = 0; k < 4; ++k) {
                ir  += wih[g * 4 + k]        * x2[k];
                iz  += wih[(g + 32) * 4 + k] * x2[k];
                inn += wih[(g + 64) * 4 + k] * x2[k];
            }
            float hr = bhh[g], hz = bhh[g + 32], hnn = bhh[g + 64];
            #pragma unroll
            for (int k = 0; k < 32; ++k) {
                hr  += whh[g * 32 + k]        * h[k];
                hz  += whh[(g + 32) * 32 + k] * h[k];
                hnn += whh[(g + 64) * 32 + k] * h[k];
            }
            float r = sigmoidf_(ir + hr);
            float z = sigmoidf_(iz + hz);
            float n = tanhf_(inn + r * hnn);
            hn[g] = (1.f - z) * n + z * h[g];
        }
        #pragma unroll
        for (int g = 0; g < 32; ++g) h[g] = hn[g];

        float o = fb[0];
        #pragma unroll
        for (int j = 0; j < 32; ++j) o += fW[j] * h[j];

        out[t * B + b] = o;

        if (t < T_DEC - 1) {
            const float* yy = y + (size_t)b * 52 + (t + 1) * 4;
            x[0] = yy[1];
            x[1] = yy[2];
            x[2] = yy[3];
            x[3] = o;
        }
    }
}

extern "C" void kernel_launch(void* const* d_in, const int* in_sizes, int n_in,
                              void* d_out, int out_size, void* d_ws, size_t ws_size,
                              hipStream_t stream)
{
    const float* y   = (const float*)d_in[0];
    const float* enc = (const float*)d_in[1];
    const float* hid = (const float*)d_in[2];
    // d_in[3] = batch_ids (int32, unused by reference)
    const float* aW  = (const float*)d_in[4];
    const float* ab  = (const float*)d_in[5];
    const float* cW  = (const float*)d_in[6];
    const float* cb  = (const float*)d_in[7];
    const float* wih = (const float*)d_in[8];
    const float* whh = (const float*)d_in[9];
    const float* bih = (const float*)d_in[10];
    const float* bhh = (const float*)d_in[11];
    const float* fW  = (const float*)d_in[12];
    const float* fb  = (const float*)d_in[13];
    float* out = (float*)d_out;

    const size_t needP = (size_t)ENC_LEN * B * 4 * sizeof(float);  // 12.58 MB
    if (ws_size >= needP) {
        float4* P = (float4*)d_ws;
        precompute_P_kernel<<<4096, 256, 0, stream>>>(enc, cW, P);
        decode_kernel<true><<<B / 256, 256, 0, stream>>>(
            y, hid, P, enc, aW, ab, cW, cb, wih, whh, bih, bhh, fW, fb, out);
    } else {
        decode_kernel<false><<<B / 256, 256, 0, stream>>>(
            y, hid, nullptr, enc, aW, ab, cW, cb, wih, whh, bih, bhh, fW, fb, out);
    }
}

// Round 3
// 698.569 us; speedup vs baseline: 1.4469x; 1.4469x over previous
//
#include <hip/hip_runtime.h>

#define B 16384
#define ENC_LEN 48
#define ENC_HID 128
#define T_DEC 12

#define NWAVE 16   // waves per block
#define EPW 3      // enc positions per wave  (16*3 = 48)
#define UPW 2      // GRU units per wave      (16*2 = 32)

__device__ __forceinline__ float fast_rcp(float x) { return __builtin_amdgcn_rcpf(x); }
__device__ __forceinline__ float fast_exp(float x) { return __expf(x); }
__device__ __forceinline__ float sigmoidf_(float x) { return fast_rcp(1.f + fast_exp(-x)); }
__device__ __forceinline__ float tanhf_(float x) {
    // 1 - 2/(e^{2x}+1); correct saturation for |x| large
    return 1.f - 2.f * fast_rcp(1.f + fast_exp(2.f * x));
}
__device__ __forceinline__ float nan_to_num_(float v) { return (v != v) ? 0.f : v; }

// ---------------- precompute P (unchanged from round 2) ----------------
// P[e*B + b] = float4( enc_row(e,b) . comb_W[i, 0:128] ), i = 0..3
__global__ __launch_bounds__(256) void precompute_P_kernel(
    const float* __restrict__ enc,    // (48, B, 128) f32
    const float* __restrict__ cW,     // (4, 132) f32
    float4* __restrict__ P)
{
    const int l = threadIdx.x & 7;
    const int rowLocal = threadIdx.x >> 3;

    float w[4][4][4];
    #pragma unroll
    for (int i = 0; i < 4; ++i)
        #pragma unroll
        for (int k = 0; k < 4; ++k) {
            float4 t = *(const float4*)(cW + i * 132 + k * 32 + l * 4);
            w[i][k][0] = t.x; w[i][k][1] = t.y; w[i][k][2] = t.z; w[i][k][3] = t.w;
        }

    const int totalRows = ENC_LEN * B;
    const int stride = gridDim.x * 32;
    for (int row = blockIdx.x * 32 + rowLocal; row < totalRows; row += stride) {
        const float* r = enc + (size_t)row * ENC_HID;
        float4 e[4];
        #pragma unroll
        for (int k = 0; k < 4; ++k)
            e[k] = *(const float4*)(r + k * 32 + l * 4);

        float a[4];
        #pragma unroll
        for (int i = 0; i < 4; ++i) {
            float s0 = e[0].x * w[i][0][0] + e[0].y * w[i][0][1] + e[0].z * w[i][0][2] + e[0].w * w[i][0][3];
            float s1 = e[1].x * w[i][1][0] + e[1].y * w[i][1][1] + e[1].z * w[i][1][2] + e[1].w * w[i][1][3];
            float s2 = e[2].x * w[i][2][0] + e[2].y * w[i][2][1] + e[2].z * w[i][2][2] + e[2].w * w[i][2][3];
            float s3 = e[3].x * w[i][3][0] + e[3].y * w[i][3][1] + e[3].z * w[i][3][2] + e[3].w * w[i][3][3];
            a[i] = (s0 + s1) + (s2 + s3);
        }
        #pragma unroll
        for (int m = 1; m < 8; m <<= 1) {
            #pragma unroll
            for (int i = 0; i < 4; ++i)
                a[i] += __shfl_xor(a[i], m, 8);
        }
        if (l == 0) P[row] = make_float4(a[0], a[1], a[2], a[3]);
    }
}

// ---------------- cooperative decode ----------------
// Block: 1024 threads = 16 waves, 64 batch elements (lane = b-within-block).
// Every wave sees the same 64 b's; wave w owns enc positions [3w,3w+3) and
// GRU units {2w, 2w+1}. Weight addresses depend only on w (scalarized via
// readfirstlane) -> s_load path. h lives in LDS (stride 36: 16B-aligned,
// bank-uniform float4 reads). S/ctx/fc reduced via LDS atomics into a
// parity-double-buffered array; 2 barriers per step.
__global__ __launch_bounds__(1024, 4) void decode_kernel(
    const float* __restrict__ y,        // (B,13,4)
    const float* __restrict__ hidden,   // (B,32)
    const float4* __restrict__ P,       // (48,B) f32x4
    const float* __restrict__ aW,       // (48,36)
    const float* __restrict__ ab,       // (48)
    const float* __restrict__ cW,       // (4,132)
    const float* __restrict__ cb,       // (4)
    const float* __restrict__ wih,      // (96,4)
    const float* __restrict__ whh,      // (96,32)
    const float* __restrict__ bih,      // (96)
    const float* __restrict__ bhh,      // (96)
    const float* __restrict__ fW,       // (32)
    const float* __restrict__ fb,       // (1)
    float* __restrict__ out)            // (12,B)
{
    __shared__ float sh_h[64 * 36];       // h[b][0:32], row stride 36
    __shared__ float sh_red[2][64][6];    // per-b: S, cc0..3, o_partial

    const int lane = threadIdx.x & 63;
    const int w = __builtin_amdgcn_readfirstlane(threadIdx.x >> 6);  // wave id, scalar
    const int b = blockIdx.x * 64 + lane;

    // stage hidden -> sh_h (wave w writes h columns 2w, 2w+1 of every row)
    {
        float2 v = *(const float2*)(hidden + (size_t)b * 32 + w * 2);
        *(float2*)(&sh_h[lane * 36 + w * 2]) = v;
    }
    // zero both reduction buffers
    for (int i = threadIdx.x; i < 2 * 64 * 6; i += 1024)
        (&sh_red[0][0][0])[i] = 0.f;

    // preload this wave's P fragments (addresses are t-invariant)
    float4 pb[EPW];
    #pragma unroll
    for (int i = 0; i < EPW; ++i)
        pb[i] = P[(size_t)(w * EPW + i) * B + b];

    // per-lane x (replicated across waves)
    float xA[4];
    #pragma unroll
    for (int k = 0; k < 4; ++k)
        xA[k] = nan_to_num_(y[(size_t)b * 52 + k]);

    __syncthreads();

    for (int t = 0; t < T_DEC; ++t) {
        const int buf = t & 1;

        // ---- A: read full h into registers ----
        float h[32];
        #pragma unroll
        for (int k = 0; k < 8; ++k) {
            float4 v = *(const float4*)(&sh_h[lane * 36 + k * 4]);
            h[k * 4 + 0] = v.x; h[k * 4 + 1] = v.y; h[k * 4 + 2] = v.z; h[k * 4 + 3] = v.w;
        }

        // ---- B: this wave's attention logits + softmax partials ----
        float Sp = 0.f, c0 = 0.f, c1 = 0.f, c2 = 0.f, c3 = 0.f;
        #pragma unroll
        for (int i = 0; i < EPW; ++i) {
            const int e = w * EPW + i;
            const float* wr = aW + e * 36;
            float s = ab[e] + wr[0] * xA[0] + wr[1] * xA[1] + wr[2] * xA[2] + wr[3] * xA[3];
            #pragma unroll
            for (int j = 0; j < 32; ++j) s += wr[4 + j] * h[j];
            float g = fast_exp(s);
            Sp += g;
            c0 += g * pb[i].x; c1 += g * pb[i].y; c2 += g * pb[i].z; c3 += g * pb[i].w;
        }
        atomicAdd(&sh_red[buf][lane][0], Sp);
        atomicAdd(&sh_red[buf][lane][1], c0);
        atomicAdd(&sh_red[buf][lane][2], c1);
        atomicAdd(&sh_red[buf][lane][3], c2);
        atomicAdd(&sh_red[buf][lane][4], c3);

        __syncthreads();   // C: softmax partials complete

        // ---- D: x2, then this wave's GRU units ----
        const float S  = sh_red[buf][lane][0];
        const float rs = fast_rcp(S);
        float x2g[4];
        #pragma unroll
        for (int i = 0; i < 4; ++i) {
            const float* cr = cW + i * 132 + 128;
            x2g[i] = sh_red[buf][lane][1 + i] * rs
                   + cr[0] * xA[0] + cr[1] * xA[1] + cr[2] * xA[2] + cr[3] * xA[3] + cb[i];
        }
        // zero the other buffer for step t+1 (safe: its last readers were pre-C)
        if (w == 0) {
            #pragma unroll
            for (int k = 0; k < 6; ++k) sh_red[buf ^ 1][lane][k] = 0.f;
        }

        float hn[UPW];
        #pragma unroll
        for (int u = 0; u < UPW; ++u) {
            const int g = w * UPW + u;
            float ir = bih[g], iz = bih[g + 32], in_ = bih[g + 64];
            #pragma unroll
            for (int k = 0; k < 4; ++k) {
                ir  += wih[g * 4 + k]        * x2g[k];
                iz  += wih[(g + 32) * 4 + k] * x2g[k];
                in_ += wih[(g + 64) * 4 + k] * x2g[k];
            }
            float hr = bhh[g], hz = bhh[g + 32], hn_ = bhh[g + 64];
            #pragma unroll
            for (int k = 0; k < 32; ++k) {
                hr  += whh[g * 32 + k]        * h[k];
                hz  += whh[(g + 32) * 32 + k] * h[k];
                hn_ += whh[(g + 64) * 32 + k] * h[k];
            }
            float r = sigmoidf_(ir + hr);
            float z = sigmoidf_(iz + hz);
            float n = tanhf_(in_ + r * hn_);
            hn[u] = (1.f - z) * n + z * h[g];
        }
        *(float2*)(&sh_h[lane * 36 + w * UPW]) = make_float2(hn[0], hn[1]);

        atomicAdd(&sh_red[buf][lane][5], fW[w * UPW] * hn[0] + fW[w * UPW + 1] * hn[1]);

        __syncthreads();   // E: h written, fc reduced

        // ---- F: output + next x ----
        const float o = sh_red[buf][lane][5] + fb[0];
        if (w == 0) out[t * B + b] = o;

        if (t < T_DEC - 1) {
            float4 yv = *(const float4*)(y + (size_t)b * 52 + (t + 1) * 4);
            xA[0] = yv.y; xA[1] = yv.z; xA[2] = yv.w; xA[3] = o;
        }
    }
}

extern "C" void kernel_launch(void* const* d_in, const int* in_sizes, int n_in,
                              void* d_out, int out_size, void* d_ws, size_t ws_size,
                              hipStream_t stream)
{
    const float* y   = (const float*)d_in[0];
    const float* enc = (const float*)d_in[1];
    const float* hid = (const float*)d_in[2];
    // d_in[3] = batch_ids (int32, unused by reference)
    const float* aW  = (const float*)d_in[4];
    const float* ab  = (const float*)d_in[5];
    const float* cW  = (const float*)d_in[6];
    const float* cb  = (const float*)d_in[7];
    const float* wih = (const float*)d_in[8];
    const float* whh = (const float*)d_in[9];
    const float* bih = (const float*)d_in[10];
    const float* bhh = (const float*)d_in[11];
    const float* fW  = (const float*)d_in[12];
    const float* fb  = (const float*)d_in[13];
    float* out = (float*)d_out;

    float4* P = (float4*)d_ws;   // 48*B float4 = 12.58 MB (ws proved sufficient in R2)

    precompute_P_kernel<<<4096, 256, 0, stream>>>(enc, cW, P);
    decode_kernel<<<B / 64, 1024, 0, stream>>>(
        y, hid, P, aW, ab, cW, cb, wih, whh, bih, bhh, fW, fb, out);
}